// Round 1
// baseline (942.192 us; speedup 1.0000x reference)
//
#include <hip/hip_runtime.h>
#include <math.h>

#define NB 46
#define NS 50
#define ND 768
#define GAMA 0.96875f
#define NM 2300   // NB*NS rows

// ---------------- Kernel 1: QKV projections (+bias, +pe for Q,K) ----------
// out[m,n] = sum_k X[m,k]*W[n,k] + bias[n] (+ pe[m/50, n] for z<2)
// grid (36, 12, 3), block 256. 64x64 tile, k-step 16, 4x4 micro-tile.
__global__ __launch_bounds__(256) void qkv_gemm(
    const float* __restrict__ text_emb, const float* __restrict__ emb,
    const float* __restrict__ Wq, const float* __restrict__ bq,
    const float* __restrict__ Wk, const float* __restrict__ bk,
    const float* __restrict__ Wv, const float* __restrict__ bv,
    float* __restrict__ Q, float* __restrict__ K, float* __restrict__ V)
{
    const int z = blockIdx.z;
    const float* X    = (z == 0) ? text_emb : emb;
    const float* W    = (z == 0) ? Wq : (z == 1) ? Wk : Wv;
    const float* bias = (z == 0) ? bq : (z == 1) ? bk : bv;
    float* out        = (z == 0) ? Q  : (z == 1) ? K  : V;

    // stride 68 floats: 16B-aligned rows (68*4=272=17*16) + conflict-free staging
    __shared__ float Xs[16][68];
    __shared__ float Ws[16][68];

    const int tid = threadIdx.x;
    const int tx = tid & 15, ty = tid >> 4;
    const int m0 = blockIdx.x * 64, n0 = blockIdx.y * 64;

    const int lrow = tid >> 2;        // 0..63
    const int lk   = (tid & 3) * 4;   // 0,4,8,12

    float acc[4][4];
    #pragma unroll
    for (int i = 0; i < 4; i++)
        #pragma unroll
        for (int j = 0; j < 4; j++) acc[i][j] = 0.f;

    for (int k0 = 0; k0 < ND; k0 += 16) {
        float4 xv = make_float4(0.f, 0.f, 0.f, 0.f);
        const int xm = m0 + lrow;
        if (xm < NM) xv = *reinterpret_cast<const float4*>(&X[xm * ND + k0 + lk]);
        const float4 wv = *reinterpret_cast<const float4*>(&W[(n0 + lrow) * ND + k0 + lk]);
        Xs[lk + 0][lrow] = xv.x; Xs[lk + 1][lrow] = xv.y;
        Xs[lk + 2][lrow] = xv.z; Xs[lk + 3][lrow] = xv.w;
        Ws[lk + 0][lrow] = wv.x; Ws[lk + 1][lrow] = wv.y;
        Ws[lk + 2][lrow] = wv.z; Ws[lk + 3][lrow] = wv.w;
        __syncthreads();
        #pragma unroll
        for (int k = 0; k < 16; k++) {
            const float4 a  = *reinterpret_cast<const float4*>(&Xs[k][4 * ty]);
            const float4 b4 = *reinterpret_cast<const float4*>(&Ws[k][4 * tx]);
            const float av[4]  = {a.x,  a.y,  a.z,  a.w};
            const float bv4[4] = {b4.x, b4.y, b4.z, b4.w};
            #pragma unroll
            for (int i = 0; i < 4; i++)
                #pragma unroll
                for (int j = 0; j < 4; j++) acc[i][j] += av[i] * bv4[j];
        }
        __syncthreads();
    }

    const float C2 = -0.0239861701969175f; // -2*ln(10000)/768
    #pragma unroll
    for (int i = 0; i < 4; i++) {
        const int m = m0 + 4 * ty + i;
        if (m >= NM) continue;
        const int bpos = m / NS;  // pe indexed by BATCH position (faithful to source)
        #pragma unroll
        for (int j = 0; j < 4; j++) {
            const int n = n0 + 4 * tx + j;
            float v = acc[i][j] + bias[n];
            if (z < 2) {
                const int h = n >> 1;
                const float ang = (float)bpos * expf((float)h * C2);
                v += (n & 1) ? cosf(ang) : sinf(ang);
            }
            out[m * ND + n] = v;
        }
    }
}

// ---------------- Kernel 2: scores+softmax+ctx, and Ag = gamma*Q_trans -----
// one wave per (b,q). 2300 blocks x 64 threads.
__global__ __launch_bounds__(64) void attn(
    const float* __restrict__ Q, const float* __restrict__ K,
    const float* __restrict__ V,
    const float* __restrict__ lin_w, const float* __restrict__ lin_b,
    float* __restrict__ Ag, float* __restrict__ ctx_out)
{
    const int bq = blockIdx.x;
    const int b = bq / NS, q = bq % NS;
    const int lane = threadIdx.x;

    const float* Qr = Q + (b * NS + q) * ND;
    float qv[12];
    #pragma unroll
    for (int m = 0; m < 12; m++) qv[m] = Qr[m * 64 + lane];

    // scores: lane k ends up holding score[k]*8
    float mysc = 0.f;
    for (int k = 0; k < NS; k++) {
        const float* Kr = K + (b * NS + k) * ND;
        float s = 0.f;
        #pragma unroll
        for (int m = 0; m < 12; m++) s += qv[m] * Kr[m * 64 + lane];
        #pragma unroll
        for (int off = 32; off; off >>= 1) s += __shfl_xor(s, off);
        if (lane == k) mysc = s * 8.f;
    }
    // Q_trans row q: lane j holds Qt[j]; write Ag = gamma*(Qt + lin_b)
    float myqt = 0.f;
    for (int j = 0; j < NS; j++) {
        const float* Lr = lin_w + j * ND;
        float s = 0.f;
        #pragma unroll
        for (int m = 0; m < 12; m++) s += qv[m] * Lr[m * 64 + lane];
        #pragma unroll
        for (int off = 32; off; off >>= 1) s += __shfl_xor(s, off);
        if (lane == j) myqt = s;
    }
    if (lane < NS)
        Ag[b * (NS * NS) + q * NS + lane] = GAMA * (myqt + lin_b[lane]);

    // softmax over lanes 0..49
    const float sc = (lane < NS) ? mysc : -INFINITY;
    float mx = sc;
    #pragma unroll
    for (int off = 32; off; off >>= 1) mx = fmaxf(mx, __shfl_xor(mx, off));
    const float e = (lane < NS) ? expf(sc - mx) : 0.f;
    float sum = e;
    #pragma unroll
    for (int off = 32; off; off >>= 1) sum += __shfl_xor(sum, off);
    const float p = e / sum;

    // ctx row = sum_k p_k * V[b,k,:]
    float acc[12];
    #pragma unroll
    for (int m = 0; m < 12; m++) acc[m] = 0.f;
    for (int k = 0; k < NS; k++) {
        const float pk = __shfl(p, k);
        const float* Vr = V + (b * NS + k) * ND;
        #pragma unroll
        for (int m = 0; m < 12; m++) acc[m] += pk * Vr[m * 64 + lane];
    }
    float* Cr = ctx_out + (b * NS + q) * ND;
    #pragma unroll
    for (int m = 0; m < 12; m++) Cr[m * 64 + lane] = acc[m];
}

// ---------------- Kernel 3: gamma-decay recurrence --------------------------
// rec[i,b,:,:] = Ag_b @ rec[i-1,b,:,:] + ctx[i];  independent per (b, column d).
// grid (12 chunks, 46 b) x 128 threads (2 waves, rows split 25/25).
__global__ __launch_bounds__(128) void recur(
    const float* __restrict__ Ag, const float* __restrict__ ctx,
    float* __restrict__ rec)
{
    const int chunk = blockIdx.x;          // 0..11  -> 64 columns each
    const int b     = blockIdx.y;          // 0..45
    const int lane  = threadIdx.x & 63;
    const int wid   = threadIdx.x >> 6;    // 0..1
    const int d     = chunk * 64 + lane;
    const int r0    = wid * 25;

    __shared__ float sld[NS * 64];         // state s[r][dcol], 12.8 KB

    const float* __restrict__ Ab = Ag + b * (NS * NS);  // uniform -> s_load path

    // i = 0: s_0 = ctx[0]
    for (int r = r0; r < r0 + 25; ++r) {
        const float v = ctx[r * ND + d];
        sld[r * 64 + lane] = v;
        rec[(b * NS + r) * ND + d] = v;
    }
    __syncthreads();

    for (int i = 1; i < NB; ++i) {
        float sreg[NS];
        #pragma unroll
        for (int j = 0; j < NS; j++) sreg[j] = sld[j * 64 + lane];
        __syncthreads();   // all reads done before anyone overwrites state

        for (int r = r0; r < r0 + 25; ++r) {
            const float* __restrict__ Ar = Ab + r * NS;
            float s0 = 0.f, s1 = 0.f, s2 = 0.f, s3 = 0.f;
            #pragma unroll
            for (int j = 0; j < 48; j += 4) {
                s0 += Ar[j + 0] * sreg[j + 0];
                s1 += Ar[j + 1] * sreg[j + 1];
                s2 += Ar[j + 2] * sreg[j + 2];
                s3 += Ar[j + 3] * sreg[j + 3];
            }
            s0 += Ar[48] * sreg[48];
            s1 += Ar[49] * sreg[49];
            const float v = ((s0 + s2) + (s1 + s3)) + ctx[(i * NS + r) * ND + d];
            sld[r * 64 + lane] = v;
            rec[((i * NB + b) * NS + r) * ND + d] = v;
        }
        __syncthreads();
    }
}

extern "C" void kernel_launch(void* const* d_in, const int* in_sizes, int n_in,
                              void* d_out, int out_size, void* d_ws, size_t ws_size,
                              hipStream_t stream) {
    const float* text_emb = (const float*)d_in[0];
    const float* emb      = (const float*)d_in[1];
    const float* Wq = (const float*)d_in[2]; const float* bq = (const float*)d_in[3];
    const float* Wk = (const float*)d_in[4]; const float* bk = (const float*)d_in[5];
    const float* Wv = (const float*)d_in[6]; const float* bv = (const float*)d_in[7];
    const float* lw = (const float*)d_in[8]; const float* lb = (const float*)d_in[9];

    float* out = (float*)d_out;
    float* ctx = out;                          // [46,50,768]
    float* rec = out + NB * NS * ND;           // [46,46,50,768]

    float* ws = (float*)d_ws;                  // needs 21.7 MB
    float* Q  = ws;
    float* K  = Q + NB * NS * ND;
    float* V  = K + NB * NS * ND;
    float* Ag = V + NB * NS * ND;              // gamma * Q_trans, [46,50,50]

    qkv_gemm<<<dim3(36, 12, 3), 256, 0, stream>>>(text_emb, emb, Wq, bq, Wk, bk, Wv, bv, Q, K, V);
    attn<<<dim3(NM), 64, 0, stream>>>(Q, K, V, lw, lb, Ag, ctx);
    recur<<<dim3(12, NB), 128, 0, stream>>>(Ag, ctx, rec);
}

// Round 2
// 832.018 us; speedup vs baseline: 1.1324x; 1.1324x over previous
//
#include <hip/hip_runtime.h>
#include <math.h>

#define NB 46
#define NS 50
#define ND 768
#define GAMA 0.96875f
#define NM 2300   // NB*NS rows

// ---------------- Kernel 1: QKV projections (+bias, +pe for Q,K) ----------
// out[m,n] = sum_k X[m,k]*W[n,k] + bias[n] (+ pe[m/50, n] for z<2)
// grid (36, 12, 3), block 256. 64x64 tile, k-step 16, 4x4 micro-tile.
__global__ __launch_bounds__(256) void qkv_gemm(
    const float* __restrict__ text_emb, const float* __restrict__ emb,
    const float* __restrict__ Wq, const float* __restrict__ bq,
    const float* __restrict__ Wk, const float* __restrict__ bk,
    const float* __restrict__ Wv, const float* __restrict__ bv,
    float* __restrict__ Q, float* __restrict__ K, float* __restrict__ V)
{
    const int z = blockIdx.z;
    const float* X    = (z == 0) ? text_emb : emb;
    const float* W    = (z == 0) ? Wq : (z == 1) ? Wk : Wv;
    const float* bias = (z == 0) ? bq : (z == 1) ? bk : bv;
    float* out        = (z == 0) ? Q  : (z == 1) ? K  : V;

    __shared__ float Xs[16][68];
    __shared__ float Ws[16][68];

    const int tid = threadIdx.x;
    const int tx = tid & 15, ty = tid >> 4;
    const int m0 = blockIdx.x * 64, n0 = blockIdx.y * 64;

    const int lrow = tid >> 2;        // 0..63
    const int lk   = (tid & 3) * 4;   // 0,4,8,12

    float acc[4][4];
    #pragma unroll
    for (int i = 0; i < 4; i++)
        #pragma unroll
        for (int j = 0; j < 4; j++) acc[i][j] = 0.f;

    for (int k0 = 0; k0 < ND; k0 += 16) {
        float4 xv = make_float4(0.f, 0.f, 0.f, 0.f);
        const int xm = m0 + lrow;
        if (xm < NM) xv = *reinterpret_cast<const float4*>(&X[xm * ND + k0 + lk]);
        const float4 wv = *reinterpret_cast<const float4*>(&W[(n0 + lrow) * ND + k0 + lk]);
        Xs[lk + 0][lrow] = xv.x; Xs[lk + 1][lrow] = xv.y;
        Xs[lk + 2][lrow] = xv.z; Xs[lk + 3][lrow] = xv.w;
        Ws[lk + 0][lrow] = wv.x; Ws[lk + 1][lrow] = wv.y;
        Ws[lk + 2][lrow] = wv.z; Ws[lk + 3][lrow] = wv.w;
        __syncthreads();
        #pragma unroll
        for (int k = 0; k < 16; k++) {
            const float4 a  = *reinterpret_cast<const float4*>(&Xs[k][4 * ty]);
            const float4 b4 = *reinterpret_cast<const float4*>(&Ws[k][4 * tx]);
            const float av[4]  = {a.x,  a.y,  a.z,  a.w};
            const float bv4[4] = {b4.x, b4.y, b4.z, b4.w};
            #pragma unroll
            for (int i = 0; i < 4; i++)
                #pragma unroll
                for (int j = 0; j < 4; j++) acc[i][j] += av[i] * bv4[j];
        }
        __syncthreads();
    }

    const float C2 = -0.0239861701969175f; // -2*ln(10000)/768
    #pragma unroll
    for (int i = 0; i < 4; i++) {
        const int m = m0 + 4 * ty + i;
        if (m >= NM) continue;
        const int bpos = m / NS;  // pe indexed by BATCH position (faithful to source)
        #pragma unroll
        for (int j = 0; j < 4; j++) {
            const int n = n0 + 4 * tx + j;
            float v = acc[i][j] + bias[n];
            if (z < 2) {
                const int h = n >> 1;
                const float ang = (float)bpos * expf((float)h * C2);
                v += (n & 1) ? cosf(ang) : sinf(ang);
            }
            out[m * ND + n] = v;
        }
    }
}

// ---------------- Kernel 2: scores+softmax+ctx, and Ag = gamma*Q_trans -----
// one wave per (b,q). 2300 blocks x 64 threads.
__global__ __launch_bounds__(64) void attn(
    const float* __restrict__ Q, const float* __restrict__ K,
    const float* __restrict__ V,
    const float* __restrict__ lin_w, const float* __restrict__ lin_b,
    float* __restrict__ Ag, float* __restrict__ ctx_out)
{
    const int bq = blockIdx.x;
    const int b = bq / NS, q = bq % NS;
    const int lane = threadIdx.x;

    const float* Qr = Q + (b * NS + q) * ND;
    float qv[12];
    #pragma unroll
    for (int m = 0; m < 12; m++) qv[m] = Qr[m * 64 + lane];

    // scores: lane k ends up holding score[k]*8
    float mysc = 0.f;
    for (int k = 0; k < NS; k++) {
        const float* Kr = K + (b * NS + k) * ND;
        float s = 0.f;
        #pragma unroll
        for (int m = 0; m < 12; m++) s += qv[m] * Kr[m * 64 + lane];
        #pragma unroll
        for (int off = 32; off; off >>= 1) s += __shfl_xor(s, off);
        if (lane == k) mysc = s * 8.f;
    }
    // Q_trans row q: lane j holds Qt[j]; write Ag = gamma*(Qt + lin_b)
    float myqt = 0.f;
    for (int j = 0; j < NS; j++) {
        const float* Lr = lin_w + j * ND;
        float s = 0.f;
        #pragma unroll
        for (int m = 0; m < 12; m++) s += qv[m] * Lr[m * 64 + lane];
        #pragma unroll
        for (int off = 32; off; off >>= 1) s += __shfl_xor(s, off);
        if (lane == j) myqt = s;
    }
    if (lane < NS)
        Ag[b * (NS * NS) + q * NS + lane] = GAMA * (myqt + lin_b[lane]);

    // softmax over lanes 0..49
    const float sc = (lane < NS) ? mysc : -INFINITY;
    float mx = sc;
    #pragma unroll
    for (int off = 32; off; off >>= 1) mx = fmaxf(mx, __shfl_xor(mx, off));
    const float e = (lane < NS) ? expf(sc - mx) : 0.f;
    float sum = e;
    #pragma unroll
    for (int off = 32; off; off >>= 1) sum += __shfl_xor(sum, off);
    const float p = e / sum;

    // ctx row = sum_k p_k * V[b,k,:]
    float acc[12];
    #pragma unroll
    for (int m = 0; m < 12; m++) acc[m] = 0.f;
    for (int k = 0; k < NS; k++) {
        const float pk = __shfl(p, k);
        const float* Vr = V + (b * NS + k) * ND;
        #pragma unroll
        for (int m = 0; m < 12; m++) acc[m] += pk * Vr[m * 64 + lane];
    }
    float* Cr = ctx_out + (b * NS + q) * ND;
    #pragma unroll
    for (int m = 0; m < 12; m++) Cr[m * 64 + lane] = acc[m];
}

// ---------------- Kernel 3: gamma-decay recurrence --------------------------
// rec[i,b,:,:] = Ag_b @ rec[i-1,b,:,:] + ctx[i];  independent per (b, column d).
// grid (12 chunks, 46 b) x 256 threads (4 waves, 13/13/13/11 rows).
// Latency-decoupled: ctx prefetched one step ahead (no store-drain on its
// vmcnt wait), double-buffered LDS state (one barrier/step), NT stores.
#define RPW 13
__global__ __launch_bounds__(256) void recur(
    const float* __restrict__ Ag, const float* __restrict__ ctx,
    float* __restrict__ rec)
{
    const int chunk = blockIdx.x;          // 0..11  -> 64 columns each
    const int b     = blockIdx.y;          // 0..45
    const int lane  = threadIdx.x & 63;
    const int wid   = threadIdx.x >> 6;    // 0..3
    const int d     = chunk * 64 + lane;
    const int r0    = wid * RPW;           // 0,13,26,39

    __shared__ float st[2][NS * 64];       // double-buffered state, 25.6 KB

    const float* __restrict__ Ab = Ag + b * (NS * NS);  // uniform -> s_load path

    float cv[RPW];   // ctx values for current step (my rows)
    float cvN[RPW];  // ctx values for next step (prefetch)

    // ---- step 0: s_0 = ctx[0] ----
    #pragma unroll
    for (int k = 0; k < RPW; k++) {
        const int r = r0 + k;
        if (r < NS) cv[k] = ctx[r * ND + d];
    }
    // prefetch ctx for step 1
    #pragma unroll
    for (int k = 0; k < RPW; k++) {
        const int r = r0 + k;
        if (r < NS) cvN[k] = ctx[(NS + r) * ND + d];
    }
    #pragma unroll
    for (int k = 0; k < RPW; k++) {
        const int r = r0 + k;
        if (r < NS) {
            st[0][r * 64 + lane] = cv[k];
            __builtin_nontemporal_store(cv[k], &rec[(b * NS + r) * ND + d]);
        }
    }
    __syncthreads();

    int p = 0;
    for (int i = 1; i < NB; ++i) {
        // rotate prefetch; issue loads for step i+1 BEFORE this step's stores
        #pragma unroll
        for (int k = 0; k < RPW; k++) cv[k] = cvN[k];
        if (i + 1 < NB) {
            #pragma unroll
            for (int k = 0; k < RPW; k++) {
                const int r = r0 + k;
                if (r < NS) cvN[k] = ctx[((i + 1) * NS + r) * ND + d];
            }
        }

        // full state -> registers (LDS broadcast-free, 2-lane/bank = free)
        float sreg[NS];
        #pragma unroll
        for (int j = 0; j < NS; j++) sreg[j] = st[p][j * 64 + lane];

        #pragma unroll
        for (int k = 0; k < RPW; k++) {
            const int r = r0 + k;
            if (r < NS) {
                const float* __restrict__ Ar = Ab + r * NS;
                float s0 = 0.f, s1 = 0.f, s2 = 0.f, s3 = 0.f;
                #pragma unroll
                for (int j = 0; j < 48; j += 4) {
                    s0 += Ar[j + 0] * sreg[j + 0];
                    s1 += Ar[j + 1] * sreg[j + 1];
                    s2 += Ar[j + 2] * sreg[j + 2];
                    s3 += Ar[j + 3] * sreg[j + 3];
                }
                s0 += Ar[48] * sreg[48];
                s1 += Ar[49] * sreg[49];
                const float v = ((s0 + s2) + (s1 + s3)) + cv[k];
                st[p ^ 1][r * 64 + lane] = v;
                __builtin_nontemporal_store(v, &rec[((i * NB + b) * NS + r) * ND + d]);
            }
        }
        __syncthreads();
        p ^= 1;
    }
}

extern "C" void kernel_launch(void* const* d_in, const int* in_sizes, int n_in,
                              void* d_out, int out_size, void* d_ws, size_t ws_size,
                              hipStream_t stream) {
    const float* text_emb = (const float*)d_in[0];
    const float* emb      = (const float*)d_in[1];
    const float* Wq = (const float*)d_in[2]; const float* bq = (const float*)d_in[3];
    const float* Wk = (const float*)d_in[4]; const float* bk = (const float*)d_in[5];
    const float* Wv = (const float*)d_in[6]; const float* bv = (const float*)d_in[7];
    const float* lw = (const float*)d_in[8]; const float* lb = (const float*)d_in[9];

    float* out = (float*)d_out;
    float* ctx = out;                          // [46,50,768]
    float* rec = out + NB * NS * ND;           // [46,46,50,768]

    float* ws = (float*)d_ws;                  // needs 21.7 MB
    float* Q  = ws;
    float* K  = Q + NB * NS * ND;
    float* V  = K + NB * NS * ND;
    float* Ag = V + NB * NS * ND;              // gamma * Q_trans, [46,50,50]

    qkv_gemm<<<dim3(36, 12, 3), 256, 0, stream>>>(text_emb, emb, Wq, bq, Wk, bk, Wv, bv, Q, K, V);
    attn<<<dim3(NM), 64, 0, stream>>>(Q, K, V, lw, lb, Ag, ctx);
    recur<<<dim3(12, NB), 256, 0, stream>>>(Ag, ctx, rec);
}